// Round 6
// baseline (248.861 us; speedup 1.0000x reference)
//
#include <hip/hip_runtime.h>
#include <cstddef>

#define NB 2
#define T_ 4096
#define H_ 32
#define P_ 64
#define N_ 64
#define L_ 64
#define C_ 64
#define SC 4   // chunks per block (strip); grid = NB*H_*(C_/SC) = 1024 = 4 blocks/CU

typedef __attribute__((ext_vector_type(8))) short short8;   // MFMA A/B frag
typedef __attribute__((ext_vector_type(4))) short short4v;
typedef __attribute__((ext_vector_type(4))) float f32x4;    // MFMA C/D frag

static __device__ inline short f2bf(float f) {
    unsigned u = __builtin_bit_cast(unsigned, f);
    u += 0x7fffu + ((u >> 16) & 1u);
    return (short)(u >> 16);
}
// XOR-swizzled LDS: rows of 64 shorts (128B). key = (row ^ row>>3)&7 on 16B slots.
static __device__ inline int swz(int row, int col) {
    return (row << 6) + (col ^ (((row ^ (row >> 3)) & 7) << 3));
}
static __device__ inline short8 ldfragS(const short* s, int t16, int kt, int lane) {
    const int row = t16 * 16 + (lane & 15);
    const int col = kt * 32 + ((lane >> 4) << 3);
    return *(const short8*)(s + swz(row, col));
}

// ---------------------------------------------------------------------------
// Strip-carried SSD kernel, v3. Identical math/structure to v2; the ONE
// change is amdgpu_waves_per_eu(4,4): the allocator was pinning at the
// 64-VGPR/8-wave boundary and spilling ~35 regs to scratch (+46MB FETCH,
// +47MB WRITE, VALUBusy 12%). LDS caps occupancy at 4 blocks/CU anyway,
// so a 128-VGPR budget (4 waves/EU) costs nothing and kills the spill.
// ---------------------------------------------------------------------------
__global__ __attribute__((amdgpu_waves_per_eu(4, 4))) __launch_bounds__(256)
void ssd_fused(
    const float* __restrict__ X, const float* __restrict__ A,
    const float* __restrict__ Bm, const float* __restrict__ Cm,
    float* __restrict__ Y)
{
    __shared__ short sU [L_ * 64];   // X^T [p][i]
    __shared__ short sV [L_ * 64];   // (B*dec)^T [n][i]
    __shared__ short sB [L_ * 64];   // B natural [s][n]
    __shared__ short sNS[L_ * 64];   // carried state dump [p][n]
    __shared__ short sZ [L_ * 64];   // S_scaled [i][s]

    const int tid = threadIdx.x, lane = tid & 63, wv = tid >> 6;
    const int idx = blockIdx.x;
    const int h  = idx & (H_ - 1);
    const int cq = (idx >> 5) & (C_ / SC - 1);
    const int bb = idx >> 9;
    const int cb = cq * SC;

    const int G = lane >> 4, col = lane & 15;
    const int i0 = 16 * wv + 4 * G;     // output-row / transposed-col base
    const int p0 = 4 * col;             // transposed-row base

    const int c1 = (cb >= 1) ? cb - 1 : 0;
    const int c2 = (cb >= 2) ? cb - 2 : 0;

    // ---- init round 1 loads (chunk cb-1) ----
    float4 xr[4], br[4];
    {
        const size_t g = ((size_t)(bb * T_ + c1 * L_ + i0) * H_ + h) * P_ + p0;
        #pragma unroll
        for (int k = 0; k < 4; k++) {
            xr[k] = *(const float4*)(X  + g + (size_t)k * (H_ * P_));
            br[k] = *(const float4*)(Bm + g + (size_t)k * (H_ * P_));
        }
    }
    // ---- scans: chunk cb (cs), cb-1 (cs1), cb-2 (cs2) ----
    float cs  = A[(size_t)(bb * T_ + cb * L_ + lane) * H_ + h];
    float cs1 = A[(size_t)(bb * T_ + c1 * L_ + lane) * H_ + h];
    float cs2 = A[(size_t)(bb * T_ + c2 * L_ + lane) * H_ + h];
    #pragma unroll
    for (int d = 1; d < 64; d <<= 1) {
        const float u0 = __shfl_up(cs,  (unsigned)d);
        const float u1 = __shfl_up(cs1, (unsigned)d);
        const float u2 = __shfl_up(cs2, (unsigned)d);
        if (lane >= d) { cs += u0; cs1 += u1; cs2 += u2; }
    }
    const float tot1 = __shfl(cs1, 63);
    const float tot2 = __shfl(cs2, 63);

    // ---- init stage 1: sU <- X[c1]^T, sV <- (B[c1] * m1 e^{tot1-cs1})^T ----
    {
        const float m = (cb >= 1) ? 1.f : 0.f;
        float dec[4];
        #pragma unroll
        for (int k = 0; k < 4; k++) dec[k] = m * __expf(tot1 - __shfl(cs1, i0 + k));
        #pragma unroll
        for (int jj = 0; jj < 4; jj++) {
            short4v vx, vb;
            #pragma unroll
            for (int k = 0; k < 4; k++) {
                vx[k] = f2bf(((const float*)&xr[k])[jj]);
                vb[k] = f2bf(((const float*)&br[k])[jj] * dec[k]);
            }
            *(short4v*)&sU[swz(p0 + jj, i0)] = vx;
            *(short4v*)&sV[swz(p0 + jj, i0)] = vb;
        }
    }
    __syncthreads();

    // prefetch init round 2 (chunk cb-2) under MFMA round 1
    {
        const size_t g = ((size_t)(bb * T_ + c2 * L_ + i0) * H_ + h) * P_ + p0;
        #pragma unroll
        for (int k = 0; k < 4; k++) {
            xr[k] = *(const float4*)(X  + g + (size_t)k * (H_ * P_));
            br[k] = *(const float4*)(Bm + g + (size_t)k * (H_ * P_));
        }
    }
    f32x4 ns[4];
    #pragma unroll
    for (int nt = 0; nt < 4; nt++) ns[nt] = (f32x4){0.f, 0.f, 0.f, 0.f};
    {
        const short8 a0 = ldfragS(sU, wv, 0, lane);
        const short8 a1 = ldfragS(sU, wv, 1, lane);
        #pragma unroll
        for (int nt = 0; nt < 4; nt++) {
            ns[nt] = __builtin_amdgcn_mfma_f32_16x16x32_bf16(a0, ldfragS(sV, nt, 0, lane), ns[nt], 0, 0, 0);
            ns[nt] = __builtin_amdgcn_mfma_f32_16x16x32_bf16(a1, ldfragS(sV, nt, 1, lane), ns[nt], 0, 0, 0);
        }
    }
    __syncthreads();

    // ---- init stage 2: sU <- X[c2]^T, sV <- (B[c2] * m2 e^{tot1+tot2-cs2})^T ----
    {
        const float m = (cb >= 2) ? 1.f : 0.f;
        const float tw = tot1 + tot2;
        float dec[4];
        #pragma unroll
        for (int k = 0; k < 4; k++) dec[k] = m * __expf(tw - __shfl(cs2, i0 + k));
        #pragma unroll
        for (int jj = 0; jj < 4; jj++) {
            short4v vx, vb;
            #pragma unroll
            for (int k = 0; k < 4; k++) {
                vx[k] = f2bf(((const float*)&xr[k])[jj]);
                vb[k] = f2bf(((const float*)&br[k])[jj] * dec[k]);
            }
            *(short4v*)&sU[swz(p0 + jj, i0)] = vx;
            *(short4v*)&sV[swz(p0 + jj, i0)] = vb;
        }
    }
    __syncthreads();

    // prefetch chunk cb (X,B,C) + scan(cb+1) under MFMA round 2
    float4 cr0, cr1, cr2, cr3;
    float csN;
    {
        const size_t g = ((size_t)(bb * T_ + cb * L_ + i0) * H_ + h) * P_ + p0;
        #pragma unroll
        for (int k = 0; k < 4; k++) {
            xr[k] = *(const float4*)(X  + g + (size_t)k * (H_ * P_));
            br[k] = *(const float4*)(Bm + g + (size_t)k * (H_ * P_));
        }
        const size_t gc = ((size_t)(bb * T_ + cb * L_ + wv * 16 + col) * H_ + h) * P_ + (G << 3);
        cr0 = *(const float4*)(Cm + gc);
        cr1 = *(const float4*)(Cm + gc + 4);
        cr2 = *(const float4*)(Cm + gc + 32);
        cr3 = *(const float4*)(Cm + gc + 36);
        float aN = A[(size_t)(bb * T_ + (cb + 1) * L_ + lane) * H_ + h];  // cb+1 <= 61
        #pragma unroll
        for (int d = 1; d < 64; d <<= 1) {
            const float u = __shfl_up(aN, (unsigned)d);
            if (lane >= d) aN += u;
        }
        csN = aN;
    }
    {
        const short8 a0 = ldfragS(sU, wv, 0, lane);
        const short8 a1 = ldfragS(sU, wv, 1, lane);
        #pragma unroll
        for (int nt = 0; nt < 4; nt++) {
            ns[nt] = __builtin_amdgcn_mfma_f32_16x16x32_bf16(a0, ldfragS(sV, nt, 0, lane), ns[nt], 0, 0, 0);
            ns[nt] = __builtin_amdgcn_mfma_f32_16x16x32_bf16(a1, ldfragS(sV, nt, 1, lane), ns[nt], 0, 0, 0);
        }
    }
    // cfs for chunk cb: C fragments scaled by e^{cs_row} (row = 16wv+col)
    short8 cfs0, cfs1;
    {
        const float sc = __expf(__shfl(cs, 16 * wv + col));
        #pragma unroll
        for (int k = 0; k < 4; k++) {
            cfs0[k]     = f2bf(((const float*)&cr0)[k] * sc);
            cfs0[4 + k] = f2bf(((const float*)&cr1)[k] * sc);
            cfs1[k]     = f2bf(((const float*)&cr2)[k] * sc);
            cfs1[4 + k] = f2bf(((const float*)&cr3)[k] * sc);
        }
    }

    // ================= main loop over the strip =================
    #pragma unroll
    for (int j = 0; j < SC; j++) {
        const int c = cb + j;
        const int t0 = c * L_;
        __syncthreads();                 // all prior reads of LDS buffers done
        const float tot = __shfl(cs, 63);

        // ---- stage chunk c (xr/br die here) ----
        {
            float dec[4];
            #pragma unroll
            for (int k = 0; k < 4; k++) dec[k] = __expf(tot - __shfl(cs, i0 + k));
            #pragma unroll
            for (int jj = 0; jj < 4; jj++) {
                short4v vx, vb;
                #pragma unroll
                for (int k = 0; k < 4; k++) {
                    vx[k] = f2bf(((const float*)&xr[k])[jj]);
                    vb[k] = f2bf(((const float*)&br[k])[jj] * dec[k]);
                }
                *(short4v*)&sU[swz(p0 + jj, i0)] = vx;
                *(short4v*)&sV[swz(p0 + jj, i0)] = vb;
            }
            // B natural from the same registers
            #pragma unroll
            for (int k = 0; k < 4; k++) {
                short4v vb;
                #pragma unroll
                for (int q = 0; q < 4; q++) vb[q] = f2bf(((const float*)&br[k])[q]);
                *(short4v*)&sB[swz(i0 + k, p0)] = vb;
            }
            // dump carried state (= state entering chunk c)
            #pragma unroll
            for (int nt = 0; nt < 4; nt++)
                #pragma unroll
                for (int r = 0; r < 4; r++)
                    sNS[swz(i0 + r, nt * 16 + col)] = f2bf(ns[nt][r]);
        }
        __syncthreads();                 // staged tiles visible

        // ---- issue chunk c+1 loads (consumed next iteration) ----
        float aN = 0.f;
        if (j < SC - 1) {
            const size_t g = ((size_t)(bb * T_ + (c + 1) * L_ + i0) * H_ + h) * P_ + p0;
            #pragma unroll
            for (int k = 0; k < 4; k++) {
                xr[k] = *(const float4*)(X  + g + (size_t)k * (H_ * P_));
                br[k] = *(const float4*)(Bm + g + (size_t)k * (H_ * P_));
            }
            const size_t gc = ((size_t)(bb * T_ + (c + 1) * L_ + wv * 16 + col) * H_ + h) * P_ + (G << 3);
            cr0 = *(const float4*)(Cm + gc);
            cr1 = *(const float4*)(Cm + gc + 4);
            cr2 = *(const float4*)(Cm + gc + 32);
            cr3 = *(const float4*)(Cm + gc + 36);
            if (j < SC - 2)
                aN = A[(size_t)(bb * T_ + (c + 2) * L_ + lane) * H_ + h];
        }

        // ---- acc = cfs·NS  (carries e^{cs_i}·C·NS) ----
        f32x4 acc[4];
        #pragma unroll
        for (int pt = 0; pt < 4; pt++) {
            f32x4 a = {0.f, 0.f, 0.f, 0.f};
            a = __builtin_amdgcn_mfma_f32_16x16x32_bf16(cfs0, ldfragS(sNS, pt, 0, lane), a, 0, 0, 0);
            a = __builtin_amdgcn_mfma_f32_16x16x32_bf16(cfs1, ldfragS(sNS, pt, 1, lane), a, 0, 0, 0);
            acc[pt] = a;
        }

        // ---- S_scaled = (cfs·B^T)·e^{-cs_s}, tril mask, scatter -> sZ ----
        #pragma unroll
        for (int st = 0; st < 4; st++) {
            f32x4 a = {0.f, 0.f, 0.f, 0.f};
            a = __builtin_amdgcn_mfma_f32_16x16x32_bf16(cfs0, ldfragS(sB, st, 0, lane), a, 0, 0, 0);
            a = __builtin_amdgcn_mfma_f32_16x16x32_bf16(cfs1, ldfragS(sB, st, 1, lane), a, 0, 0, 0);
            const int scol = st * 16 + col;
            const float en = __expf(-__shfl(cs, scol));
            #pragma unroll
            for (int r = 0; r < 4; r++) {
                const float v = (scol <= i0 + r) ? a[r] * en : 0.f;
                sZ[swz(i0 + r, scol)] = f2bf(v);
            }
        }

        // ---- Y = S·X + acc (same-wave sZ read), direct store ----
        const short8 s0f = ldfragS(sZ, wv, 0, lane);
        const short8 s1f = ldfragS(sZ, wv, 1, lane);
        #pragma unroll
        for (int pt = 0; pt < 4; pt++) {
            f32x4 a = acc[pt];
            a = __builtin_amdgcn_mfma_f32_16x16x32_bf16(s0f, ldfragS(sU, pt, 0, lane), a, 0, 0, 0);
            a = __builtin_amdgcn_mfma_f32_16x16x32_bf16(s1f, ldfragS(sU, pt, 1, lane), a, 0, 0, 0);
            #pragma unroll
            for (int r = 0; r < 4; r++) {
                const size_t g = ((size_t)(bb * T_ + t0 + i0 + r) * H_ + h) * P_ + pt * 16 + col;
                Y[g] = a[r];
            }
        }

        // ---- state update: ns = e^{tot}·ns + X^T·(B dec)^T (skip on last) ----
        if (j < SC - 1) {
            const float scale = __expf(tot);
            const short8 a0 = ldfragS(sU, wv, 0, lane);
            const short8 a1 = ldfragS(sU, wv, 1, lane);
            #pragma unroll
            for (int nt = 0; nt < 4; nt++) {
                f32x4 t = ns[nt];
                #pragma unroll
                for (int r = 0; r < 4; r++) t[r] *= scale;
                t = __builtin_amdgcn_mfma_f32_16x16x32_bf16(a0, ldfragS(sV, nt, 0, lane), t, 0, 0, 0);
                t = __builtin_amdgcn_mfma_f32_16x16x32_bf16(a1, ldfragS(sV, nt, 1, lane), t, 0, 0, 0);
                ns[nt] = t;
            }
            // cfs for chunk c+1 (cr dies here); scan c+2
            const float sc = __expf(__shfl(csN, 16 * wv + col));
            #pragma unroll
            for (int k = 0; k < 4; k++) {
                cfs0[k]     = f2bf(((const float*)&cr0)[k] * sc);
                cfs0[4 + k] = f2bf(((const float*)&cr1)[k] * sc);
                cfs1[k]     = f2bf(((const float*)&cr2)[k] * sc);
                cfs1[4 + k] = f2bf(((const float*)&cr3)[k] * sc);
            }
        }
        float csN2 = 0.f;
        if (j < SC - 2) {
            #pragma unroll
            for (int d = 1; d < 64; d <<= 1) {
                const float u = __shfl_up(aN, (unsigned)d);
                if (lane >= d) aN += u;
            }
            csN2 = aN;
        }
        cs = csN;
        csN = csN2;
    }
}

extern "C" void kernel_launch(void* const* d_in, const int* in_sizes, int n_in,
                              void* d_out, int out_size, void* d_ws, size_t ws_size,
                              hipStream_t stream)
{
    const float* X  = (const float*)d_in[0];
    const float* A  = (const float*)d_in[1];
    const float* Bm = (const float*)d_in[2];
    const float* Cm = (const float*)d_in[3];
    float* Y = (float*)d_out;
    (void)d_ws; (void)ws_size;

    ssd_fused<<<NB * H_ * (C_ / SC), 256, 0, stream>>>(X, A, Bm, Cm, Y);
}

// Round 7
// 247.434 us; speedup vs baseline: 1.0058x; 1.0058x over previous
//
#include <hip/hip_runtime.h>
#include <cstddef>

#define NB 2
#define T_ 4096
#define H_ 32
#define P_ 64
#define N_ 64
#define L_ 64
#define C_ 64
#define SC 4   // chunks per block (strip); grid = NB*H_*(C_/SC) = 1024 = 4 blocks/CU

typedef __attribute__((ext_vector_type(8))) short short8;   // MFMA A/B frag
typedef __attribute__((ext_vector_type(4))) short short4v;
typedef __attribute__((ext_vector_type(4))) float f32x4;    // MFMA C/D frag

static __device__ inline short f2bf(float f) {
    unsigned u = __builtin_bit_cast(unsigned, f);
    u += 0x7fffu + ((u >> 16) & 1u);
    return (short)(u >> 16);
}
// XOR-swizzled LDS: rows of 64 shorts (128B). key = (row ^ row>>3)&7 on 16B slots.
static __device__ inline int swz(int row, int col) {
    return (row << 6) + (col ^ (((row ^ (row >> 3)) & 7) << 3));
}
static __device__ inline short8 ldfragS(const short* s, int t16, int kt, int lane) {
    const int row = t16 * 16 + (lane & 15);
    const int col = kt * 32 + ((lane >> 4) << 3);
    return *(const short8*)(s + swz(row, col));
}

// ---------------------------------------------------------------------------
// Strip-carried SSD kernel, v4 (low-pressure). Allocator refuses >64 VGPRs
// (two failed A/Bs), so the fix is structural: peak live set cut from ~110
// to ~70 by (1) no cross-iteration X/B/C register prefetch — loads issued
// at point of use, latency hidden by ns-dump/dec VALU work + 4 blocks/CU
// TLP + L2/L3 residency; (2) per-pt fused accumulator chain
// a = cfs*NS -> += S*X -> store (acc[16] -> a[4]); (3) C-load for c+1
// spans only the 8 ns-update MFMAs; (4) unroll 1 to stop hoist bloat.
// Math identical to v3.
// ---------------------------------------------------------------------------
__global__ __launch_bounds__(256, 4) void ssd_fused(
    const float* __restrict__ X, const float* __restrict__ A,
    const float* __restrict__ Bm, const float* __restrict__ Cm,
    float* __restrict__ Y)
{
    __shared__ short sU [L_ * 64];   // X^T [p][i]
    __shared__ short sV [L_ * 64];   // (B*dec)^T [n][i]
    __shared__ short sB [L_ * 64];   // B natural [s][n]
    __shared__ short sNS[L_ * 64];   // carried state dump [p][n]
    __shared__ short sZ [L_ * 64];   // S_scaled [i][s]

    const int tid = threadIdx.x, lane = tid & 63, wv = tid >> 6;
    const int idx = blockIdx.x;
    const int h  = idx & (H_ - 1);
    const int cq = (idx >> 5) & (C_ / SC - 1);
    const int bb = idx >> 9;
    const int cb = cq * SC;

    const int G = lane >> 4, col = lane & 15;
    const int i0 = 16 * wv + 4 * G;     // output-row / transposed-col base
    const int p0 = 4 * col;             // transposed-row base

    const int c1 = (cb >= 1) ? cb - 1 : 0;
    const int c2 = (cb >= 2) ? cb - 2 : 0;

    // ---- init round 1 loads (chunk cb-1) ----
    float4 xr[4], br[4];
    {
        const size_t g = ((size_t)(bb * T_ + c1 * L_ + i0) * H_ + h) * P_ + p0;
        #pragma unroll
        for (int k = 0; k < 4; k++) {
            xr[k] = *(const float4*)(X  + g + (size_t)k * (H_ * P_));
            br[k] = *(const float4*)(Bm + g + (size_t)k * (H_ * P_));
        }
    }
    // ---- scans: chunk cb (cs), cb-1 (cs1), cb-2 (cs2) ----
    float cs  = A[(size_t)(bb * T_ + cb * L_ + lane) * H_ + h];
    float cs1 = A[(size_t)(bb * T_ + c1 * L_ + lane) * H_ + h];
    float cs2 = A[(size_t)(bb * T_ + c2 * L_ + lane) * H_ + h];
    #pragma unroll
    for (int d = 1; d < 64; d <<= 1) {
        const float u0 = __shfl_up(cs,  (unsigned)d);
        const float u1 = __shfl_up(cs1, (unsigned)d);
        const float u2 = __shfl_up(cs2, (unsigned)d);
        if (lane >= d) { cs += u0; cs1 += u1; cs2 += u2; }
    }
    const float tot1 = __shfl(cs1, 63);
    const float tot2 = __shfl(cs2, 63);

    // ---- init stage 1: sU <- X[c1]^T, sV <- (B[c1] * m1 e^{tot1-cs1})^T ----
    {
        const float m = (cb >= 1) ? 1.f : 0.f;
        float dec[4];
        #pragma unroll
        for (int k = 0; k < 4; k++) dec[k] = m * __expf(tot1 - __shfl(cs1, i0 + k));
        #pragma unroll
        for (int jj = 0; jj < 4; jj++) {
            short4v vx, vb;
            #pragma unroll
            for (int k = 0; k < 4; k++) {
                vx[k] = f2bf(((const float*)&xr[k])[jj]);
                vb[k] = f2bf(((const float*)&br[k])[jj] * dec[k]);
            }
            *(short4v*)&sU[swz(p0 + jj, i0)] = vx;
            *(short4v*)&sV[swz(p0 + jj, i0)] = vb;
        }
    }
    __syncthreads();

    // prefetch init round 2 (chunk cb-2) under MFMA round 1
    {
        const size_t g = ((size_t)(bb * T_ + c2 * L_ + i0) * H_ + h) * P_ + p0;
        #pragma unroll
        for (int k = 0; k < 4; k++) {
            xr[k] = *(const float4*)(X  + g + (size_t)k * (H_ * P_));
            br[k] = *(const float4*)(Bm + g + (size_t)k * (H_ * P_));
        }
    }
    f32x4 ns[4];
    #pragma unroll
    for (int nt = 0; nt < 4; nt++) ns[nt] = (f32x4){0.f, 0.f, 0.f, 0.f};
    {
        const short8 a0 = ldfragS(sU, wv, 0, lane);
        const short8 a1 = ldfragS(sU, wv, 1, lane);
        #pragma unroll
        for (int nt = 0; nt < 4; nt++) {
            ns[nt] = __builtin_amdgcn_mfma_f32_16x16x32_bf16(a0, ldfragS(sV, nt, 0, lane), ns[nt], 0, 0, 0);
            ns[nt] = __builtin_amdgcn_mfma_f32_16x16x32_bf16(a1, ldfragS(sV, nt, 1, lane), ns[nt], 0, 0, 0);
        }
    }
    __syncthreads();

    // ---- init stage 2: sU <- X[c2]^T, sV <- (B[c2] * m2 e^{tot1+tot2-cs2})^T ----
    {
        const float m = (cb >= 2) ? 1.f : 0.f;
        const float tw = tot1 + tot2;
        float dec[4];
        #pragma unroll
        for (int k = 0; k < 4; k++) dec[k] = m * __expf(tw - __shfl(cs2, i0 + k));
        #pragma unroll
        for (int jj = 0; jj < 4; jj++) {
            short4v vx, vb;
            #pragma unroll
            for (int k = 0; k < 4; k++) {
                vx[k] = f2bf(((const float*)&xr[k])[jj]);
                vb[k] = f2bf(((const float*)&br[k])[jj] * dec[k]);
            }
            *(short4v*)&sU[swz(p0 + jj, i0)] = vx;
            *(short4v*)&sV[swz(p0 + jj, i0)] = vb;
        }
    }
    __syncthreads();

    // ---- init: C(cb) + A(cb+1) loads issued, then ns MFMA round 2 ----
    short8 cfs0, cfs1;
    float csN;
    {
        const size_t gc = ((size_t)(bb * T_ + cb * L_ + wv * 16 + col) * H_ + h) * P_ + (G << 3);
        const float4 cr0 = *(const float4*)(Cm + gc);
        const float4 cr1 = *(const float4*)(Cm + gc + 4);
        const float4 cr2 = *(const float4*)(Cm + gc + 32);
        const float4 cr3 = *(const float4*)(Cm + gc + 36);
        float aN = A[(size_t)(bb * T_ + (cb + 1) * L_ + lane) * H_ + h];  // cb+1 <= 61

        const short8 a0 = ldfragS(sU, wv, 0, lane);
        const short8 a1 = ldfragS(sU, wv, 1, lane);
        #pragma unroll
        for (int nt = 0; nt < 4; nt++) {
            ns[nt] = __builtin_amdgcn_mfma_f32_16x16x32_bf16(a0, ldfragS(sV, nt, 0, lane), ns[nt], 0, 0, 0);
            ns[nt] = __builtin_amdgcn_mfma_f32_16x16x32_bf16(a1, ldfragS(sV, nt, 1, lane), ns[nt], 0, 0, 0);
        }
        // cfs for chunk cb: C scaled by e^{cs_row} (row = 16wv+col)
        const float sc = __expf(__shfl(cs, 16 * wv + col));
        #pragma unroll
        for (int k = 0; k < 4; k++) {
            cfs0[k]     = f2bf(((const float*)&cr0)[k] * sc);
            cfs0[4 + k] = f2bf(((const float*)&cr1)[k] * sc);
            cfs1[k]     = f2bf(((const float*)&cr2)[k] * sc);
            cfs1[4 + k] = f2bf(((const float*)&cr3)[k] * sc);
        }
        #pragma unroll
        for (int d = 1; d < 64; d <<= 1) {
            const float u = __shfl_up(aN, (unsigned)d);
            if (lane >= d) aN += u;
        }
        csN = aN;
    }

    // ================= main loop over the strip =================
    #pragma unroll 1
    for (int j = 0; j < SC; j++) {
        const int c = cb + j;
        const int t0 = c * L_;
        __syncthreads();                 // all prior reads of LDS buffers done
        const float tot = __shfl(cs, 63);

        // ---- issue X,B loads for chunk c (consumed this iteration) ----
        {
            const size_t g = ((size_t)(bb * T_ + t0 + i0) * H_ + h) * P_ + p0;
            #pragma unroll
            for (int k = 0; k < 4; k++) {
                xr[k] = *(const float4*)(X  + g + (size_t)k * (H_ * P_));
                br[k] = *(const float4*)(Bm + g + (size_t)k * (H_ * P_));
            }
        }
        // dump carried state while loads are in flight
        #pragma unroll
        for (int nt = 0; nt < 4; nt++)
            #pragma unroll
            for (int r = 0; r < 4; r++)
                sNS[swz(i0 + r, nt * 16 + col)] = f2bf(ns[nt][r]);
        float dec[4];
        #pragma unroll
        for (int k = 0; k < 4; k++) dec[k] = __expf(tot - __shfl(cs, i0 + k));

        // ---- stage chunk c (xr/br die here) ----
        #pragma unroll
        for (int jj = 0; jj < 4; jj++) {
            short4v vx, vb;
            #pragma unroll
            for (int k = 0; k < 4; k++) {
                vx[k] = f2bf(((const float*)&xr[k])[jj]);
                vb[k] = f2bf(((const float*)&br[k])[jj] * dec[k]);
            }
            *(short4v*)&sU[swz(p0 + jj, i0)] = vx;
            *(short4v*)&sV[swz(p0 + jj, i0)] = vb;
        }
        #pragma unroll
        for (int k = 0; k < 4; k++) {
            short4v vb;
            #pragma unroll
            for (int q = 0; q < 4; q++) vb[q] = f2bf(((const float*)&br[k])[q]);
            *(short4v*)&sB[swz(i0 + k, p0)] = vb;
        }
        __syncthreads();                 // staged tiles visible

        // ---- S_scaled = (cfs·B^T)·e^{-cs_s}, tril mask, scatter -> sZ ----
        #pragma unroll
        for (int st = 0; st < 4; st++) {
            f32x4 a = {0.f, 0.f, 0.f, 0.f};
            a = __builtin_amdgcn_mfma_f32_16x16x32_bf16(cfs0, ldfragS(sB, st, 0, lane), a, 0, 0, 0);
            a = __builtin_amdgcn_mfma_f32_16x16x32_bf16(cfs1, ldfragS(sB, st, 1, lane), a, 0, 0, 0);
            const int scol = st * 16 + col;
            const float en = __expf(-__shfl(cs, scol));
            #pragma unroll
            for (int r = 0; r < 4; r++) {
                const float v = (scol <= i0 + r) ? a[r] * en : 0.f;
                sZ[swz(i0 + r, scol)] = f2bf(v);
            }
        }
        // same-wave rows: write->read ordering within a wave is safe
        const short8 s0f = ldfragS(sZ, wv, 0, lane);
        const short8 s1f = ldfragS(sZ, wv, 1, lane);

        // ---- fused per-pt: a = cfs·NS; a += S·X; store Y ----
        #pragma unroll
        for (int pt = 0; pt < 4; pt++) {
            f32x4 a = {0.f, 0.f, 0.f, 0.f};
            a = __builtin_amdgcn_mfma_f32_16x16x32_bf16(cfs0, ldfragS(sNS, pt, 0, lane), a, 0, 0, 0);
            a = __builtin_amdgcn_mfma_f32_16x16x32_bf16(cfs1, ldfragS(sNS, pt, 1, lane), a, 0, 0, 0);
            a = __builtin_amdgcn_mfma_f32_16x16x32_bf16(s0f, ldfragS(sU, pt, 0, lane), a, 0, 0, 0);
            a = __builtin_amdgcn_mfma_f32_16x16x32_bf16(s1f, ldfragS(sU, pt, 1, lane), a, 0, 0, 0);
            #pragma unroll
            for (int r = 0; r < 4; r++) {
                const size_t g = ((size_t)(bb * T_ + t0 + i0 + r) * H_ + h) * P_ + pt * 16 + col;
                Y[g] = a[r];
            }
        }

        // ---- tail: ns update + next chunk's C/scan (skip on last) ----
        float csN2 = 0.f;
        if (j < SC - 1) {
            // issue C(c+1) and A(c+2) loads first; latency hides under MFMAs
            const size_t gc = ((size_t)(bb * T_ + (c + 1) * L_ + wv * 16 + col) * H_ + h) * P_ + (G << 3);
            const float4 cr0 = *(const float4*)(Cm + gc);
            const float4 cr1 = *(const float4*)(Cm + gc + 4);
            const float4 cr2 = *(const float4*)(Cm + gc + 32);
            const float4 cr3 = *(const float4*)(Cm + gc + 36);
            float aN = 0.f;
            if (j < SC - 2)
                aN = A[(size_t)(bb * T_ + (c + 2) * L_ + lane) * H_ + h];

            // ns = e^{tot}·ns + X^T·(B dec)^T
            const float scale = __expf(tot);
            const short8 a0 = ldfragS(sU, wv, 0, lane);
            const short8 a1 = ldfragS(sU, wv, 1, lane);
            #pragma unroll
            for (int nt = 0; nt < 4; nt++) {
                f32x4 t = ns[nt];
                #pragma unroll
                for (int r = 0; r < 4; r++) t[r] *= scale;
                t = __builtin_amdgcn_mfma_f32_16x16x32_bf16(a0, ldfragS(sV, nt, 0, lane), t, 0, 0, 0);
                t = __builtin_amdgcn_mfma_f32_16x16x32_bf16(a1, ldfragS(sV, nt, 1, lane), t, 0, 0, 0);
                ns[nt] = t;
            }
            // cfs for chunk c+1
            const float sc = __expf(__shfl(csN, 16 * wv + col));
            #pragma unroll
            for (int k = 0; k < 4; k++) {
                cfs0[k]     = f2bf(((const float*)&cr0)[k] * sc);
                cfs0[4 + k] = f2bf(((const float*)&cr1)[k] * sc);
                cfs1[k]     = f2bf(((const float*)&cr2)[k] * sc);
                cfs1[4 + k] = f2bf(((const float*)&cr3)[k] * sc);
            }
            if (j < SC - 2) {
                #pragma unroll
                for (int d = 1; d < 64; d <<= 1) {
                    const float u = __shfl_up(aN, (unsigned)d);
                    if (lane >= d) aN += u;
                }
                csN2 = aN;
            }
        }
        cs = csN;
        csN = csN2;
    }
}

extern "C" void kernel_launch(void* const* d_in, const int* in_sizes, int n_in,
                              void* d_out, int out_size, void* d_ws, size_t ws_size,
                              hipStream_t stream)
{
    const float* X  = (const float*)d_in[0];
    const float* A  = (const float*)d_in[1];
    const float* Bm = (const float*)d_in[2];
    const float* Cm = (const float*)d_in[3];
    float* Y = (float*)d_out;
    (void)d_ws; (void)ws_size;

    ssd_fused<<<NB * H_ * (C_ / SC), 256, 0, stream>>>(X, A, Bm, Cm, Y);
}